// Round 9
// baseline (3445.716 us; speedup 1.0000x reference)
//
#include <hip/hip_runtime.h>
#include <hip/hip_bf16.h>

#define TT 256
#define BB 128
#define EMBD 256
#define HID 512
#define KTAG 12
#define START_TAG 10
#define STOP_TAG 11
#define SMEM_BYTES 147456 // 96KB W + 48KB A

typedef __attribute__((ext_vector_type(8))) short short8;
typedef __attribute__((ext_vector_type(4))) float f32x4;
typedef unsigned long long ull;

__device__ __forceinline__ unsigned short f2bf(float f) {
    union { float f; unsigned int u; } v; v.f = f;
    unsigned int r = v.u + 0x7fffu + ((v.u >> 16) & 1u);   // RNE
    return (unsigned short)(r >> 16);
}
__device__ __forceinline__ float fsig(float x) {
    return __fdividef(1.0f, 1.0f + __expf(-x));
}
__device__ __forceinline__ float ftanh(float x) {
    return 2.0f * __fdividef(1.0f, 1.0f + __expf(-2.0f * x)) - 1.0f;
}
__device__ __forceinline__ void gll16(const void* g, void* l) {
    __builtin_amdgcn_global_load_lds((const __attribute__((address_space(1))) void*)g,
                                     (__attribute__((address_space(3))) void*)l, 16, 0, 0);
}
__device__ __forceinline__ void pack8(const float* src, unsigned short* dst) {
    float4 v0 = *(const float4*)src;
    float4 v1 = *(const float4*)(src + 4);
    unsigned short tmp[8];
    tmp[0] = f2bf(v0.x); tmp[1] = f2bf(v0.y); tmp[2] = f2bf(v0.z); tmp[3] = f2bf(v0.w);
    tmp[4] = f2bf(v1.x); tmp[5] = f2bf(v1.y); tmp[6] = f2bf(v1.z); tmp[7] = f2bf(v1.w);
    *(uint4*)dst = *(const uint4*)tmp;
}

// ---------------- fused prologue: xs gather | W reorder | state/bias/fcW prep | hx clear ----------------
__global__ void prologue(const int* __restrict__ x, const float* __restrict__ emb,
                         const float* __restrict__ Wihf, const float* __restrict__ Whhf,
                         const float* __restrict__ Wihb, const float* __restrict__ Whhb,
                         const float* __restrict__ h0,
                         const float* __restrict__ bihf, const float* __restrict__ bhhf,
                         const float* __restrict__ bihb, const float* __restrict__ bhhb,
                         const float* __restrict__ fcW,
                         unsigned short* __restrict__ xs, unsigned short* __restrict__ Wr,
                         unsigned short* __restrict__ h0buf, float* __restrict__ bias2,
                         unsigned short* __restrict__ fcWr, ull* __restrict__ hx)
{
    int blk = blockIdx.x;
    int tid = threadIdx.x;
    if (blk < 4096) {                       // ---- xs gather: bf16 xs[T][B][EMBD]
        int i = blk * 256 + tid;
        int chk = i & 31;
        int row = i >> 5;                   // t*BB + b
        int b = row & (BB - 1);
        int t = row >> 7;
        pack8(emb + (size_t)x[b * TT + t] * EMBD + chk * 8, xs + (size_t)row * EMBD + chk * 8);
    } else if (blk < 5632) {                // ---- W reorder -> bf16 Wr[2][2048][768]
        int i = (blk - 4096) * 256 + tid;
        int c8 = i % 96;
        int r2 = i / 96;
        int nr = r2 & 2047;
        int dir = r2 >> 11;
        int utile = nr >> 6;
        int r6 = nr & 63;
        int wm = r6 >> 4;
        int rr = r6 & 15;
        int ul = rr >> 2, g = rr & 3;
        int orow = g * HID + utile * 16 + wm * 4 + ul;
        int k0 = c8 * 8;
        const float* Wih = dir ? Wihb : Wihf;
        const float* Whh = dir ? Whhb : Whhf;
        const float* src = (k0 < EMBD) ? (Wih + (size_t)orow * EMBD + k0)
                                       : (Whh + (size_t)orow * HID + (k0 - EMBD));
        pack8(src, Wr + ((size_t)dir * 2048 + nr) * 768 + k0);
    } else if (blk < 6144) {                // ---- state / bias / fcWr
        int i = (blk - 5632) * 256 + tid;
        if (i < 2 * BB * HID) h0buf[i] = f2bf(h0[i]);
        if (i < 2 * 2048) {
            int dir = i >> 11, j = i & 2047;
            bias2[i] = dir ? (bihb[j] + bhhb[j]) : (bihf[j] + bhhf[j]);
        }
        if (i < 16 * 1024) {
            int tag = i >> 10, k = i & 1023;
            fcWr[i] = f2bf(tag < KTAG ? fcW[tag * 1024 + k] : 0.0f);
        }
    } else {                                // ---- hx clear (stale-tag kill, per launch)
        int i = (blk - 6144) * 256 + tid;   // < 262144 ull
        hx[i] = 0ull;
    }
}

// ---------------- persistent BiLSTM ----------------
// 256 blocks x 256 threads, 1 block/CU. grp = blk&7 (dir=grp>>2, btile=grp&3), utile = blk>>3.
// MFMA operand-swapped (A=W, B=[xs|h]) -> in-register pointwise (R6-verified).
// h exchange: SELF-VALIDATING tagged 8B atomic words {2 bf16, tag=k+1} in ping-pong
// hx[dir][k&1][b][u/2]. No flags, no drains, no release ordering. Consumers poll their
// 32 words (burst-issued before xs-MFMA), scatter hits into Abuf fragment slots via ds_write.
// Overwrite-safe by induction: publish(k) follows consume(k-1) in program order.
__launch_bounds__(256, 1)
__global__ void lstm_persistent(
    const unsigned short* __restrict__ xs, const unsigned short* __restrict__ Wr,
    const float* __restrict__ bias2, const int* __restrict__ lengths,
    const unsigned short* __restrict__ h0buf, const float* __restrict__ c0,
    unsigned short* __restrict__ hsf, unsigned short* __restrict__ hsb,
    ull* __restrict__ hx)
{
    extern __shared__ char smem[];
    unsigned short* Wlds = (unsigned short*)smem;                     // 98304 B
    unsigned short* Abuf = (unsigned short*)(smem + 98304);           // 49152 B
    char* AbufB = (char*)Abuf;
    __shared__ int s_ml;

    const int blk = blockIdx.x;
    const int grp = blk & 7;
    const int dir = grp >> 2;
    const int btile = grp & 3;
    const int utile = blk >> 3;          // 0..31
    const int bg0 = btile * 32;

    const int tid = threadIdx.x;
    const int w = tid >> 6;
    const int l = tid & 63;
    const int l15 = l & 15, l16 = l >> 4;

    unsigned short* hs = dir ? hsb : hsf;
    unsigned int* hs_u32 = (unsigned int*)hs;

    // ---- group maxlen (slab max): fwd runs [0,ml), bwd fast-forwards to t=ml-1
    {
        int v = (tid < 32) ? lengths[bg0 + tid] : 0;
        if (tid < 64) {
            #pragma unroll
            for (int off = 32; off >= 1; off >>= 1) v = max(v, __shfl_xor(v, off, 64));
            if (tid == 0) s_ml = v;
        }
    }
    __syncthreads();
    const int TTs = s_ml;

    // ---- issue resident-W stage + xs(k=0) stage (drained by first loop-top sync)
    {
        const unsigned short* src0 =
            Wr + ((size_t)(dir * 2048 + utile * 64) + (w * 16 + l15)) * 768 + l16 * 8;
        #pragma unroll
        for (int ks = 0; ks < 24; ks++)
            gll16(src0 + ks * 32, Wlds + (w * 24 + ks) * 512);
    }
    {
        int mm = w & 1, ksb = (w >> 1) * 4;
        const int t0 = dir ? (TTs - 1) : 0;
        const unsigned short* asrc =
            xs + ((size_t)t0 * BB + (bg0 + mm * 16 + l15)) * EMBD + l16 * 8;
        #pragma unroll
        for (int q = 0; q < 4; q++)
            gll16(asrc + (ksb + q) * 32, Abuf + (mm * 24 + ksb + q) * 512);
    }

    // ---- per-thread state
    const int u = utile * 16 + w * 4 + l16;
    const int bA = bg0 + l15, bB = bg0 + 16 + l15;
    const int lenA = lengths[bA], lenB = lengths[bB];
    float cA = c0[((size_t)dir * BB + bA) * HID + u];
    float cB = c0[((size_t)dir * BB + bB) * HID + u];
    float bias_r[4];
    #pragma unroll
    for (int g = 0; g < 4; g++) bias_r[g] = bias2[dir * 2048 + g * 512 + u];

    // ---- poll-role constants: thread handles (b_local = tid>>3, word col q = tid&7)
    const int b_local = tid >> 3, q = tid & 7;
    const int mm_c = b_local >> 4, b15_c = b_local & 15;
    const int C0 = 2 * ((mm_c * 24 + 8) * 512 + (q >> 2) * 128 + b15_c * 8 + 2 * (q & 3));

    for (int k = 0; k < TTs; k++) {
        const int t = dir ? (TTs - 1 - k) : k;

        __syncthreads();                 // xs(t) staged; Abuf h-region free to overwrite

        // ---- burst-issue poll loads (overlap latency with xs-MFMA)
        ull pv[32];
        const ull* pbase = hx + (((size_t)dir * 2 + ((k - 1) & 1)) * 128 + bg0 + b_local) * 256 + q;
        if (k > 0) {
            #pragma unroll
            for (int j = 0; j < 32; j++)
                pv[j] = __hip_atomic_load(pbase + 8 * j, __ATOMIC_RELAXED,
                                          __HIP_MEMORY_SCOPE_AGENT);
            __builtin_amdgcn_sched_barrier(0);
        }

        f32x4 aA0 = {bias_r[0], bias_r[1], bias_r[2], bias_r[3]};
        f32x4 aB0 = {bias_r[0], bias_r[1], bias_r[2], bias_r[3]};
        f32x4 aA1 = {0.f,0.f,0.f,0.f}, aB1 = {0.f,0.f,0.f,0.f};
        auto mstep = [&](int ks, f32x4& xA, f32x4& xB) {
            short8 a  = *(const short8*)(Wlds + ((w * 24 + ks) << 9) + (l << 3));
            short8 b0 = *(const short8*)(Abuf + (ks << 9) + (l << 3));
            short8 b1 = *(const short8*)(Abuf + ((24 + ks) << 9) + (l << 3));
            xA = __builtin_amdgcn_mfma_f32_16x16x32_bf16(a, b0, xA, 0, 0, 0);
            xB = __builtin_amdgcn_mfma_f32_16x16x32_bf16(a, b1, xB, 0, 0, 0);
        };
        #pragma unroll
        for (int ks = 0; ks < 8; ks += 2) { mstep(ks, aA0, aB0); mstep(ks + 1, aA1, aB1); }

        // ---- acquire h(k-1)
        if (k == 0) {
            // stage h0 via gll16 (fragment layout identical to scatter's)
            int mm = w & 1, ksb = 8 + (w >> 1) * 8;
            const unsigned short* asrcH =
                h0buf + (size_t)dir * BB * HID + (size_t)(bg0 + mm * 16 + l15) * HID + l16 * 8;
            #pragma unroll
            for (int p = 0; p < 8; p++)
                gll16(asrcH + ((ksb + p) * 32 - 256), Abuf + (mm * 24 + ksb + p) * 512);
            __syncthreads();             // h0 staged (vmcnt drained)
        } else {
            unsigned need = 0xffffffffu;
            const unsigned tagw = (unsigned)k;
            #pragma unroll
            for (int j = 0; j < 32; j++) {
                if ((unsigned)(pv[j] >> 32) == tagw) {
                    need &= ~(1u << j);
                    *(unsigned*)(AbufB + C0 + (j >> 1) * 1024 + (j & 1) * 512) = (unsigned)pv[j];
                }
            }
            while (need) {
                #pragma unroll
                for (int j = 0; j < 32; j++) {
                    if (need & (1u << j)) {
                        ull v = __hip_atomic_load(pbase + 8 * j, __ATOMIC_RELAXED,
                                                  __HIP_MEMORY_SCOPE_AGENT);
                        if ((unsigned)(v >> 32) == tagw) {
                            need &= ~(1u << j);
                            *(unsigned*)(AbufB + C0 + (j >> 1) * 1024 + (j & 1) * 512) = (unsigned)v;
                        }
                    }
                }
            }
            __syncthreads();             // all scatters visible block-wide
        }

        #pragma unroll
        for (int ks = 8; ks < 24; ks += 2) { mstep(ks, aA0, aB0); mstep(ks + 1, aA1, aB1); }
        f32x4 accA = aA0 + aA1;
        f32x4 accB = aB0 + aB1;

        // ---- in-register pointwise (gate order i,f,g,o = acc[0..3]; bias pre-loaded)
        unsigned short hvA, hvB;
        {
            const int ksn = 8 + (u >> 5), kin = u & 31;
            const int baseA = ksn * 512 + ((kin >> 3) * 16 + l15) * 8 + (kin & 7);
            const int baseB = (24 + ksn) * 512 + ((kin >> 3) * 16 + l15) * 8 + (kin & 7);
            float cnA = fsig(accA[1]) * cA + fsig(accA[0]) * ftanh(accA[2]);
            float hnA = fsig(accA[3]) * ftanh(cnA);
            float cnB = fsig(accB[1]) * cB + fsig(accB[0]) * ftanh(accB[2]);
            float hnB = fsig(accB[3]) * ftanh(cnB);
            bool mA = t < lenA, mB = t < lenB;
            hvA = mA ? f2bf(hnA) : Abuf[baseA];  // carried h from staged fragment
            hvB = mB ? f2bf(hnB) : Abuf[baseB];
            cA = mA ? cnA : cA;
            cB = mB ? cnB : cB;
        }

        // ---- publish: pair (u,u+1) via shfl, tagged 8B atomic + plain hs store
        {
            int sA = __shfl_xor((int)hvA, 16, 64);
            int sB = __shfl_xor((int)hvB, 16, 64);
            if ((l16 & 1) == 0) {
                unsigned pkA = (unsigned)hvA | ((unsigned)sA << 16);
                unsigned pkB = (unsigned)hvB | ((unsigned)sB << 16);
                int wd = utile * 8 + w * 2 + (l16 >> 1);
                ull tv = ((ull)(unsigned)(k + 1)) << 32;
                size_t hxbase = ((size_t)dir * 2 + (k & 1)) * 128;
                __hip_atomic_store(hx + (hxbase + bA) * 256 + wd, (ull)pkA | tv,
                                   __ATOMIC_RELAXED, __HIP_MEMORY_SCOPE_AGENT);
                __hip_atomic_store(hx + (hxbase + bB) * 256 + wd, (ull)pkB | tv,
                                   __ATOMIC_RELAXED, __HIP_MEMORY_SCOPE_AGENT);
                hs_u32[((size_t)t * BB + bA) * 256 + wd] = pkA;
                hs_u32[((size_t)t * BB + bB) * 256 + wd] = pkB;
            }
        }

        // ---- prefetch xs(t_next); drained by next loop-top syncthreads
        if (k < TTs - 1) {
            const int tn = dir ? (TTs - 2 - k) : (k + 1);
            int mm = w & 1, ksb = (w >> 1) * 4;
            const unsigned short* asrc =
                xs + ((size_t)tn * BB + (bg0 + mm * 16 + l15)) * EMBD + l16 * 8;
            #pragma unroll
            for (int p = 0; p < 4; p++)
                gll16(asrc + (ksb + p) * 32, Abuf + (mm * 24 + ksb + p) * 512);
        }
    }
}

// ---------------- emissions as skinny MFMA GEMM: [32768 rows x K=1024] @ fcWr^T ----------------
__global__ void emissions_mfma(const unsigned short* __restrict__ hsf,
                               const unsigned short* __restrict__ hsb,
                               const unsigned short* __restrict__ fcWr,
                               const float* __restrict__ fcb, float* __restrict__ emis)
{
    int wid = (blockIdx.x * blockDim.x + threadIdx.x) >> 6;   // 2048 waves
    int l = threadIdx.x & 63;
    int l15 = l & 15, l16 = l >> 4;
    int rowbase = wid * 16;
    f32x4 acc0 = {0.f,0.f,0.f,0.f}, acc1 = {0.f,0.f,0.f,0.f};
    auto estep = [&](const unsigned short* hsp, int ks, f32x4& acc) {
        short8 av = *(const short8*)(hsp + (size_t)(rowbase + l15) * HID + (ks & 15) * 32 + l16 * 8);
        short8 bv = *(const short8*)(fcWr + l15 * 1024 + ks * 32 + l16 * 8);
        acc = __builtin_amdgcn_mfma_f32_16x16x32_bf16(av, bv, acc, 0, 0, 0);
    };
    #pragma unroll
    for (int ks = 0; ks < 16; ks += 2) { estep(hsf, ks, acc0); estep(hsf, ks + 1, acc1); }
    #pragma unroll
    for (int ks = 16; ks < 32; ks += 2) { estep(hsb, ks, acc0); estep(hsb, ks + 1, acc1); }
    f32x4 acc = acc0 + acc1;
    float bval = fcb[l15 < KTAG ? l15 : 0];
    if (l15 < KTAG) {
        #pragma unroll
        for (int r = 0; r < 4; r++)
            emis[(size_t)(rowbase + 4 * l16 + r) * KTAG + l15] = acc[r] + bval;
    }
}

// ---------------- fused CRF partition (wave 0) + gold (wave 1) ----------------
__global__ void crf_gold(const float* __restrict__ emis, const int* __restrict__ lengths,
                         const int* __restrict__ tags, const float* __restrict__ trans,
                         float* __restrict__ out)
{
    __shared__ float s_logz, s_gold;
    int b = blockIdx.x;
    int tid = threadIdx.x;   // 128
    int len = lengths[b];
    if (tid < 64) {
        int lane = tid;
        float trow[KTAG];
        #pragma unroll
        for (int j = 0; j < KTAG; j++)
            trow[j] = (lane < KTAG) ? trans[lane * KTAG + j] : -1e30f;
        float alpha = (lane == START_TAG) ? 0.0f : -10000.0f;
        float e_cur = (lane < KTAG) ? emis[(size_t)b * KTAG + lane] : 0.0f;
        for (int t = 0; t < len; t++) {
            int tn = (t + 1 < TT) ? t + 1 : t;
            float e_next = (lane < KTAG) ? emis[(size_t)(tn * BB + b) * KTAG + lane] : 0.0f;
            float sc[KTAG];
            #pragma unroll
            for (int j = 0; j < KTAG; j++) sc[j] = __shfl(alpha, j, 64) + trow[j];
            float m = sc[0];
            #pragma unroll
            for (int j = 1; j < KTAG; j++) m = fmaxf(m, sc[j]);
            float ssum = 0.0f;
            #pragma unroll
            for (int j = 0; j < KTAG; j++) ssum += __expf(sc[j] - m);
            float anew = m + __logf(ssum) + e_cur;
            alpha = (lane < KTAG) ? anew : alpha;
            e_cur = e_next;
        }
        float v = (lane < KTAG) ? (alpha + trans[STOP_TAG * KTAG + lane]) : -1e30f;
        float m = v;
        #pragma unroll
        for (int off = 1; off < 16; off <<= 1) m = fmaxf(m, __shfl_xor(m, off, 64));
        float e = __expf(v - m);
        #pragma unroll
        for (int off = 1; off < 16; off <<= 1) e += __shfl_xor(e, off, 64);
        if (lane == 0) s_logz = m + __logf(e);
    } else {
        int l2 = tid - 64;
        float part = 0.0f;
        #pragma unroll
        for (int qq = 0; qq < 4; qq++) {
            int t = l2 + qq * 64;
            if (t < len) {
                int nxt = tags[b * TT + t];
                int prev = t ? tags[b * TT + t - 1] : START_TAG;
                part += trans[nxt * KTAG + prev] + emis[(size_t)(t * BB + b) * KTAG + nxt];
            }
        }
        #pragma unroll
        for (int off = 1; off < 64; off <<= 1) part += __shfl_xor(part, off, 64);
        if (l2 == 0) s_gold = part + trans[STOP_TAG * KTAG + tags[b * TT + len - 1]];
    }
    __syncthreads();
    if (tid == 0) out[b] = s_logz - s_gold;
}

extern "C" void kernel_launch(void* const* d_in, const int* in_sizes, int n_in,
                              void* d_out, int out_size, void* d_ws, size_t ws_size,
                              hipStream_t stream)
{
    (void)in_sizes; (void)n_in; (void)out_size; (void)ws_size;
    const int*   x     = (const int*)d_in[0];
    const int*   lens  = (const int*)d_in[1];
    const int*   tags  = (const int*)d_in[2];
    const float* emb   = (const float*)d_in[3];
    const float* Wihf  = (const float*)d_in[4];
    const float* Whhf  = (const float*)d_in[5];
    const float* bihf  = (const float*)d_in[6];
    const float* bhhf  = (const float*)d_in[7];
    const float* Wihb  = (const float*)d_in[8];
    const float* Whhb  = (const float*)d_in[9];
    const float* bihb  = (const float*)d_in[10];
    const float* bhhb  = (const float*)d_in[11];
    const float* fcW   = (const float*)d_in[12];
    const float* fcb   = (const float*)d_in[13];
    const float* trans = (const float*)d_in[14];
    const float* h0    = (const float*)d_in[15];
    const float* c0    = (const float*)d_in[16];
    float* out = (float*)d_out;

    char* ws = (char*)d_ws;
    size_t off = 0;
    auto alloc = [&](size_t bytes) {
        void* p = ws + off;
        off += (bytes + 255) & ~(size_t)255;
        return p;
    };
    unsigned short* xs    = (unsigned short*)alloc((size_t)TT * BB * EMBD * 2);
    unsigned short* Wr    = (unsigned short*)alloc((size_t)2 * 2048 * 768 * 2);
    float*          bias2 = (float*)alloc((size_t)2 * 2048 * 4);
    unsigned short* h0buf = (unsigned short*)alloc((size_t)2 * BB * HID * 2);
    unsigned short* hsf   = (unsigned short*)alloc((size_t)TT * BB * HID * 2);
    unsigned short* hsb   = (unsigned short*)alloc((size_t)TT * BB * HID * 2);
    float*          emis  = (float*)alloc((size_t)TT * BB * KTAG * 4);
    unsigned short* fcWr  = (unsigned short*)alloc((size_t)16 * 1024 * 2);
    ull*            hx    = (ull*)alloc((size_t)2 * 2 * BB * (HID / 2) * 8);   // 2 MB

    prologue<<<7168, 256, 0, stream>>>(x, emb, Wihf, Whhf, Wihb, Whhb, h0,
                                       bihf, bhhf, bihb, bhhb, fcW,
                                       xs, Wr, h0buf, bias2, fcWr, hx);

    hipFuncSetAttribute(reinterpret_cast<const void*>(lstm_persistent),
                        hipFuncAttributeMaxDynamicSharedMemorySize, SMEM_BYTES);
    {
        const unsigned short* p_xs = xs; const unsigned short* p_Wr = Wr;
        const float* p_bias2 = bias2; const int* p_lens = lens;
        const unsigned short* p_h0 = h0buf; const float* p_c0 = c0;
        unsigned short* p_hsf = hsf; unsigned short* p_hsb = hsb;
        ull* p_hx = hx;
        void* args[9] = { &p_xs, &p_Wr, &p_bias2, &p_lens, &p_h0, &p_c0,
                          &p_hsf, &p_hsb, &p_hx };
        hipError_t e = hipLaunchCooperativeKernel(
            reinterpret_cast<const void*>(lstm_persistent),
            dim3(256), dim3(256), args, (unsigned)SMEM_BYTES, stream);
        if (e != hipSuccess) {
            lstm_persistent<<<256, 256, SMEM_BYTES, stream>>>(
                xs, Wr, bias2, lens, h0buf, c0, hsf, hsb, hx);
        }
    }

    emissions_mfma<<<512, 256, 0, stream>>>(hsf, hsb, fcWr, fcb, emis);
    crf_gold<<<BB, 128, 0, stream>>>(emis, lens, tags, trans, out);
}

// Round 10
// 2782.718 us; speedup vs baseline: 1.2383x; 1.2383x over previous
//
#include <hip/hip_runtime.h>
#include <hip/hip_bf16.h>

#define TT 256
#define BB 128
#define EMBD 256
#define HID 512
#define KTAG 12
#define START_TAG 10
#define STOP_TAG 11
#define SMEM_BYTES 148608 // 96KB W + 48KB A + 1.2KB hrep

typedef __attribute__((ext_vector_type(8))) short short8;
typedef __attribute__((ext_vector_type(4))) float f32x4;

__device__ __forceinline__ unsigned short f2bf(float f) {
    union { float f; unsigned int u; } v; v.f = f;
    unsigned int r = v.u + 0x7fffu + ((v.u >> 16) & 1u);   // RNE
    return (unsigned short)(r >> 16);
}
__device__ __forceinline__ float fsig(float x) {
    return __fdividef(1.0f, 1.0f + __expf(-x));
}
__device__ __forceinline__ float ftanh(float x) {
    return 2.0f * __fdividef(1.0f, 1.0f + __expf(-2.0f * x)) - 1.0f;
}
__device__ __forceinline__ void gll16(const void* g, void* l) {
    __builtin_amdgcn_global_load_lds((const __attribute__((address_space(1))) void*)g,
                                     (__attribute__((address_space(3))) void*)l, 16, 0, 0);
}
__device__ __forceinline__ void pack8(const float* src, unsigned short* dst) {
    float4 v0 = *(const float4*)src;
    float4 v1 = *(const float4*)(src + 4);
    unsigned short tmp[8];
    tmp[0] = f2bf(v0.x); tmp[1] = f2bf(v0.y); tmp[2] = f2bf(v0.z); tmp[3] = f2bf(v0.w);
    tmp[4] = f2bf(v1.x); tmp[5] = f2bf(v1.y); tmp[6] = f2bf(v1.z); tmp[7] = f2bf(v1.w);
    *(uint4*)dst = *(const uint4*)tmp;
}

#define SCHED_FENCE() __builtin_amdgcn_sched_barrier(0)
#define WAIT_VM4() do { asm volatile("s_waitcnt vmcnt(4)" ::: "memory"); SCHED_FENCE(); } while (0)
#define WAIT_VM0() do { asm volatile("s_waitcnt vmcnt(0)" ::: "memory"); SCHED_FENCE(); } while (0)
#define BARRIER_RAW() do { __builtin_amdgcn_s_barrier(); SCHED_FENCE(); } while (0)

// ---------------- fused prologue: xs gather | W reorder | state/bias/fcW prep ----------------
__global__ void prologue(const int* __restrict__ x, const float* __restrict__ emb,
                         const float* __restrict__ Wihf, const float* __restrict__ Whhf,
                         const float* __restrict__ Wihb, const float* __restrict__ Whhb,
                         const float* __restrict__ h0,
                         const float* __restrict__ bihf, const float* __restrict__ bhhf,
                         const float* __restrict__ bihb, const float* __restrict__ bhhb,
                         const float* __restrict__ fcW,
                         unsigned short* __restrict__ xs, unsigned short* __restrict__ Wr,
                         unsigned short* __restrict__ h0buf, float* __restrict__ bias2,
                         unsigned short* __restrict__ fcWr, unsigned int* __restrict__ ctrl)
{
    int blk = blockIdx.x;
    int tid = threadIdx.x;
    if (blk < 4096) {                       // ---- xs gather: bf16 xs[T][B][EMBD]
        int i = blk * 256 + tid;
        int chk = i & 31;
        int row = i >> 5;                   // t*BB + b
        int b = row & (BB - 1);
        int t = row >> 7;
        pack8(emb + (size_t)x[b * TT + t] * EMBD + chk * 8, xs + (size_t)row * EMBD + chk * 8);
    } else if (blk < 5632) {                // ---- W reorder -> bf16 Wr[2][2048][768]
        int i = (blk - 4096) * 256 + tid;
        int c8 = i % 96;
        int r2 = i / 96;
        int nr = r2 & 2047;
        int dir = r2 >> 11;
        int utile = nr >> 6;
        int r6 = nr & 63;
        int wm = r6 >> 4;
        int rr = r6 & 15;
        int ul = rr >> 2, g = rr & 3;
        int orow = g * HID + utile * 16 + wm * 4 + ul;
        int k0 = c8 * 8;
        const float* Wih = dir ? Wihb : Wihf;
        const float* Whh = dir ? Whhb : Whhf;
        const float* src = (k0 < EMBD) ? (Wih + (size_t)orow * EMBD + k0)
                                       : (Whh + (size_t)orow * HID + (k0 - EMBD));
        pack8(src, Wr + ((size_t)dir * 2048 + nr) * 768 + k0);
    } else {                                // ---- state / bias / fcWr / ctrl
        int i = (blk - 5632) * 256 + tid;
        if (i < 2 * BB * HID) h0buf[i] = f2bf(h0[i]);
        if (i < 2 * 2048) {
            int dir = i >> 11, j = i & 2047;
            bias2[i] = dir ? (bihb[j] + bhhb[j]) : (bihf[j] + bhhf[j]);
        }
        if (i < 16 * 1024) {
            int tag = i >> 10, k = i & 1023;
            fcWr[i] = f2bf(tag < KTAG ? fcW[tag * 1024 + k] : 0.0f);
        }
        if (i < 24576) ctrl[i] = 0u;
    }
}

// ---------------- persistent BiLSTM ----------------
// 256 blocks x 256 threads, 1 block/CU. grp = blk&7 (dir=grp>>2, btile=grp&3), utile = blk>>3.
// MFMA operand-swapped (A=W, B=[xs|h]) -> in-register pointwise (R6-verified).
// Sync (R10): per-wave flags at 64B spacing; ONE detector wave per group (block utile==0)
// polls all 128 flags; followers poll a replicated ready word with a single lane.
// All sync ops = relaxed agent atomics (R5/R6/R8-proven protocol).
__launch_bounds__(256, 1)
__global__ void lstm_persistent(
    const unsigned short* __restrict__ xs, const unsigned short* __restrict__ Wr,
    const float* __restrict__ bias2, const int* __restrict__ lengths,
    const unsigned short* __restrict__ h0buf, const float* __restrict__ c0,
    unsigned short* __restrict__ hsf, unsigned short* __restrict__ hsb,
    unsigned int* __restrict__ ctrl)
{
    extern __shared__ char smem[];
    unsigned short* Wlds = (unsigned short*)smem;                     // 98304 B
    unsigned short* Abuf = (unsigned short*)(smem + 98304);           // 49152 B
    unsigned short* hrep = (unsigned short*)(smem + 147456);          // [32][18] = 1152 B
    __shared__ int s_ml;

    const int blk = blockIdx.x;
    const int grp = blk & 7;
    const int dir = grp >> 2;
    const int btile = grp & 3;
    const int utile = blk >> 3;          // 0..31
    const int bg0 = btile * 32;

    const int tid = threadIdx.x;
    const int w = tid >> 6;
    const int l = tid & 63;
    const int l15 = l & 15, l16 = l >> 4;

    unsigned int* flags  = ctrl + grp * 2048;            // 128 flags x 16 u32 (64B apart)
    unsigned int* myflag = flags + (utile * 4 + w) * 16;
    unsigned int* ready  = ctrl + 16384 + grp * 64;      // 4 replicas x 16 u32
    const bool isDet = (utile == 0);

    unsigned short* hs = dir ? hsb : hsf;
    unsigned int* hs_u32 = (unsigned int*)hs;

    // ---- group maxlen: fwd runs t in [0,TTs), bwd starts at t = TTs-1 (masked steps carry)
    {
        int v = (tid < 32) ? lengths[bg0 + tid] : 0;
        if (tid < 64) {
            #pragma unroll
            for (int off = 32; off >= 1; off >>= 1) v = max(v, __shfl_xor(v, off, 64));
            if (tid == 0) s_ml = v;
        }
    }
    __syncthreads();
    const int TTs = s_ml;

    // ---- issue resident-W stage + xs(k=0) stage (drained by first loop-top sync)
    {
        const unsigned short* src0 =
            Wr + ((size_t)(dir * 2048 + utile * 64) + (w * 16 + l15)) * 768 + l16 * 8;
        #pragma unroll
        for (int ks = 0; ks < 24; ks++)
            gll16(src0 + ks * 32, Wlds + (w * 24 + ks) * 512);
    }
    {
        int mm = w & 1, ksb = (w >> 1) * 4;
        const int t0 = dir ? (TTs - 1) : 0;
        const unsigned short* asrc =
            xs + ((size_t)t0 * BB + (bg0 + mm * 16 + l15)) * EMBD + l16 * 8;
        #pragma unroll
        for (int q = 0; q < 4; q++)
            gll16(asrc + (ksb + q) * 32, Abuf + (mm * 24 + ksb + q) * 512);
    }

    // ---- per-thread state: (unit u, batches bA=bg0+l15 and bB=bg0+16+l15)
    const int u = utile * 16 + w * 4 + l16;
    const int bA = bg0 + l15, bB = bg0 + 16 + l15;
    const int lenA = lengths[bA], lenB = lengths[bB];
    float cA = c0[((size_t)dir * BB + bA) * HID + u];
    float cB = c0[((size_t)dir * BB + bB) * HID + u];
    float bias_r[4];
    #pragma unroll
    for (int g = 0; g < 4; g++) bias_r[g] = bias2[dir * 2048 + g * 512 + u];

    for (int k = 0; k < TTs; k++) {
        const int t = dir ? (TTs - 1 - k) : k;

        __syncthreads();                 // xs(t) staged (W too at k==0); full drain

        f32x4 aA0 = {bias_r[0], bias_r[1], bias_r[2], bias_r[3]};
        f32x4 aB0 = {bias_r[0], bias_r[1], bias_r[2], bias_r[3]};
        f32x4 aA1 = {0.f,0.f,0.f,0.f}, aB1 = {0.f,0.f,0.f,0.f};
        auto mstep = [&](int ks, f32x4& xA, f32x4& xB) {
            short8 a  = *(const short8*)(Wlds + ((w * 24 + ks) << 9) + (l << 3));
            short8 b0 = *(const short8*)(Abuf + (ks << 9) + (l << 3));
            short8 b1 = *(const short8*)(Abuf + ((24 + ks) << 9) + (l << 3));
            xA = __builtin_amdgcn_mfma_f32_16x16x32_bf16(a, b0, xA, 0, 0, 0);
            xB = __builtin_amdgcn_mfma_f32_16x16x32_bf16(a, b1, xB, 0, 0, 0);
        };
        #pragma unroll
        for (int ks = 0; ks < 8; ks += 2) { mstep(ks, aA0, aB0); mstep(ks + 1, aA1, aB1); }

        // ---- wait for group h(t_prev): detector polls 128 flags; followers poll ready
        if (k > 0) {
            unsigned tgt = (unsigned)k;
            if (isDet) {
                if (tid < 64) {
                    const unsigned int* f0 = flags + tid * 16;
                    const unsigned int* f1 = flags + (tid + 64) * 16;
                    while (true) {
                        unsigned a = __hip_atomic_load(f0, __ATOMIC_RELAXED,
                                                       __HIP_MEMORY_SCOPE_AGENT);
                        unsigned b = __hip_atomic_load(f1, __ATOMIC_RELAXED,
                                                       __HIP_MEMORY_SCOPE_AGENT);
                        if (__all(a >= tgt && b >= tgt)) break;
                    }
                    if (l < 4)
                        __hip_atomic_store(ready + l * 16, tgt, __ATOMIC_RELAXED,
                                           __HIP_MEMORY_SCOPE_AGENT);
                }
            } else {
                if (tid == 0) {
                    const unsigned int* rp = ready + (utile & 3) * 16;
                    while (__hip_atomic_load(rp, __ATOMIC_RELAXED,
                                             __HIP_MEMORY_SCOPE_AGENT) < tgt) { }
                }
            }
            __syncthreads();
        }
        const unsigned short* hsrc = (k == 0)
            ? (h0buf + (size_t)dir * BB * HID)
            : (hs + (size_t)(dir ? (t + 1) : (t - 1)) * BB * HID);

        // ---- stage h part (ks 8..23), two-phase overlap with MFMA
        {
            int mm = w & 1, ksb = 8 + (w >> 1) * 8;
            const unsigned short* asrcH = hsrc + (size_t)(bg0 + mm * 16 + l15) * HID + l16 * 8;
            #pragma unroll
            for (int q = 0; q < 8; q++)
                gll16(asrcH + ((ksb + q) * 32 - 256), Abuf + (mm * 24 + ksb + q) * 512);
        }
        SCHED_FENCE();
        WAIT_VM4();                      // own first-4 h loads landed
        BARRIER_RAW();                   // all waves' first-4 landed: ks{8-11,16-19} ready
        #pragma unroll
        for (int q = 0; q < 4; q++) { mstep(8 + q, aA0, aB0); mstep(16 + q, aA1, aB1); }
        WAIT_VM0();                      // remaining h loads landed
        BARRIER_RAW();                   // ks{12-15,20-23} ready
        #pragma unroll
        for (int q = 0; q < 4; q++) { mstep(12 + q, aA0, aB0); mstep(20 + q, aA1, aB1); }
        f32x4 accA = aA0 + aA1;
        f32x4 accB = aB0 + aB1;

        // ---- in-register pointwise (gate order i,f,g,o = acc[0..3]; bias already in acc)
        {
            const int ksn = 8 + (u >> 5), kin = u & 31;
            const int baseA = ksn * 512 + ((kin >> 3) * 16 + l15) * 8 + (kin & 7);
            const int baseB = (24 + ksn) * 512 + ((kin >> 3) * 16 + l15) * 8 + (kin & 7);
            float cnA = fsig(accA[1]) * cA + fsig(accA[0]) * ftanh(accA[2]);
            float hnA = fsig(accA[3]) * ftanh(cnA);
            float cnB = fsig(accB[1]) * cB + fsig(accB[0]) * ftanh(accB[2]);
            float hnB = fsig(accB[3]) * ftanh(cnB);
            bool mA = t < lenA, mB = t < lenB;
            unsigned short hvA = mA ? f2bf(hnA) : Abuf[baseA];  // carried h from staged frag
            unsigned short hvB = mB ? f2bf(hnB) : Abuf[baseB];
            cA = mA ? cnA : cA;
            cB = mB ? cnB : cB;
            hrep[l15 * 18 + w * 4 + l16]        = hvA;
            hrep[(16 + l15) * 18 + w * 4 + l16] = hvB;
        }
        __syncthreads();                 // hrep visible (lgkm drain; vmcnt already 0)

        // ---- packed publish, then xs(t+1) issue, then counted drain, then per-wave flag
        {
            int bl = tid >> 3, up = tid & 7;
            unsigned v0 = hrep[bl * 18 + up * 2];
            unsigned v1 = hrep[bl * 18 + up * 2 + 1];
            unsigned pk = v0 | (v1 << 16);
            size_t widx = (((size_t)t * BB + (bg0 + bl)) * HID + utile * 16 + up * 2) >> 1;
            __hip_atomic_store(hs_u32 + widx, pk, __ATOMIC_RELAXED, __HIP_MEMORY_SCOPE_AGENT);
        }
        SCHED_FENCE();
        if (k < TTs - 1) {
            const int tn = dir ? (TTs - 2 - k) : (k + 1);
            int mm = w & 1, ksb = (w >> 1) * 4;
            const unsigned short* asrc =
                xs + ((size_t)tn * BB + (bg0 + mm * 16 + l15)) * EMBD + l16 * 8;
            #pragma unroll
            for (int q = 0; q < 4; q++)
                gll16(asrc + (ksb + q) * 32, Abuf + (mm * 24 + ksb + q) * 512);
            SCHED_FENCE();
            WAIT_VM4();                  // oldest (publish store) acked; xs still in flight
            if (l == 0)
                __hip_atomic_store(myflag, (unsigned)(k + 1), __ATOMIC_RELAXED,
                                   __HIP_MEMORY_SCOPE_AGENT);
        }
        // loop-top __syncthreads re-syncs block and drains xs loads
    }
}

// ---------------- emissions as skinny MFMA GEMM: [32768 rows x K=1024] @ fcWr^T ----------------
__global__ void emissions_mfma(const unsigned short* __restrict__ hsf,
                               const unsigned short* __restrict__ hsb,
                               const unsigned short* __restrict__ fcWr,
                               const float* __restrict__ fcb, float* __restrict__ emis)
{
    int wid = (blockIdx.x * blockDim.x + threadIdx.x) >> 6;   // 2048 waves
    int l = threadIdx.x & 63;
    int l15 = l & 15, l16 = l >> 4;
    int rowbase = wid * 16;
    f32x4 acc0 = {0.f,0.f,0.f,0.f}, acc1 = {0.f,0.f,0.f,0.f};
    auto estep = [&](const unsigned short* hsp, int ks, f32x4& acc) {
        short8 av = *(const short8*)(hsp + (size_t)(rowbase + l15) * HID + (ks & 15) * 32 + l16 * 8);
        short8 bv = *(const short8*)(fcWr + l15 * 1024 + ks * 32 + l16 * 8);
        acc = __builtin_amdgcn_mfma_f32_16x16x32_bf16(av, bv, acc, 0, 0, 0);
    };
    #pragma unroll
    for (int ks = 0; ks < 16; ks += 2) { estep(hsf, ks, acc0); estep(hsf, ks + 1, acc1); }
    #pragma unroll
    for (int ks = 16; ks < 32; ks += 2) { estep(hsb, ks, acc0); estep(hsb, ks + 1, acc1); }
    f32x4 acc = acc0 + acc1;
    float bval = fcb[l15 < KTAG ? l15 : 0];
    if (l15 < KTAG) {
        #pragma unroll
        for (int r = 0; r < 4; r++)
            emis[(size_t)(rowbase + 4 * l16 + r) * KTAG + l15] = acc[r] + bval;
    }
}

// ---------------- fused CRF partition (wave 0) + gold (wave 1) ----------------
__global__ void crf_gold(const float* __restrict__ emis, const int* __restrict__ lengths,
                         const int* __restrict__ tags, const float* __restrict__ trans,
                         float* __restrict__ out)
{
    __shared__ float s_logz, s_gold;
    int b = blockIdx.x;
    int tid = threadIdx.x;   // 128
    int len = lengths[b];
    if (tid < 64) {
        int lane = tid;
        float trow[KTAG];
        #pragma unroll
        for (int j = 0; j < KTAG; j++)
            trow[j] = (lane < KTAG) ? trans[lane * KTAG + j] : -1e30f;
        float alpha = (lane == START_TAG) ? 0.0f : -10000.0f;
        float e_cur = (lane < KTAG) ? emis[(size_t)b * KTAG + lane] : 0.0f;
        for (int t = 0; t < len; t++) {
            int tn = (t + 1 < TT) ? t + 1 : t;
            float e_next = (lane < KTAG) ? emis[(size_t)(tn * BB + b) * KTAG + lane] : 0.0f;
            float sc[KTAG];
            #pragma unroll
            for (int j = 0; j < KTAG; j++) sc[j] = __shfl(alpha, j, 64) + trow[j];
            float m = sc[0];
            #pragma unroll
            for (int j = 1; j < KTAG; j++) m = fmaxf(m, sc[j]);
            float ssum = 0.0f;
            #pragma unroll
            for (int j = 0; j < KTAG; j++) ssum += __expf(sc[j] - m);
            float anew = m + __logf(ssum) + e_cur;
            alpha = (lane < KTAG) ? anew : alpha;
            e_cur = e_next;
        }
        float v = (lane < KTAG) ? (alpha + trans[STOP_TAG * KTAG + lane]) : -1e30f;
        float m = v;
        #pragma unroll
        for (int off = 1; off < 16; off <<= 1) m = fmaxf(m, __shfl_xor(m, off, 64));
        float e = __expf(v - m);
        #pragma unroll
        for (int off = 1; off < 16; off <<= 1) e += __shfl_xor(e, off, 64);
        if (lane == 0) s_logz = m + __logf(e);
    } else {
        int l2 = tid - 64;
        float part = 0.0f;
        #pragma unroll
        for (int q = 0; q < 4; q++) {
            int t = l2 + q * 64;
            if (t < len) {
                int nxt = tags[b * TT + t];
                int prev = t ? tags[b * TT + t - 1] : START_TAG;
                part += trans[nxt * KTAG + prev] + emis[(size_t)(t * BB + b) * KTAG + nxt];
            }
        }
        #pragma unroll
        for (int off = 1; off < 64; off <<= 1) part += __shfl_xor(part, off, 64);
        if (l2 == 0) s_gold = part + trans[STOP_TAG * KTAG + tags[b * TT + len - 1]];
    }
    __syncthreads();
    if (tid == 0) out[b] = s_logz - s_gold;
}

extern "C" void kernel_launch(void* const* d_in, const int* in_sizes, int n_in,
                              void* d_out, int out_size, void* d_ws, size_t ws_size,
                              hipStream_t stream)
{
    (void)in_sizes; (void)n_in; (void)out_size; (void)ws_size;
    const int*   x     = (const int*)d_in[0];
    const int*   lens  = (const int*)d_in[1];
    const int*   tags  = (const int*)d_in[2];
    const float* emb   = (const float*)d_in[3];
    const float* Wihf  = (const float*)d_in[4];
    const float* Whhf  = (const float*)d_in[5];
    const float* bihf  = (const float*)d_in[6];
    const float* bhhf  = (const float*)d_in[7];
    const float* Wihb  = (const float*)d_in[8];
    const float* Whhb  = (const float*)d_in[9];
    const float* bihb  = (const float*)d_in[10];
    const float* bhhb  = (const float*)d_in[11];
    const float* fcW   = (const float*)d_in[12];
    const float* fcb   = (const float*)d_in[13];
    const float* trans = (const float*)d_in[14];
    const float* h0    = (const float*)d_in[15];
    const float* c0    = (const float*)d_in[16];
    float* out = (float*)d_out;

    char* ws = (char*)d_ws;
    size_t off = 0;
    auto alloc = [&](size_t bytes) {
        void* p = ws + off;
        off += (bytes + 255) & ~(size_t)255;
        return p;
    };
    unsigned short* xs    = (unsigned short*)alloc((size_t)TT * BB * EMBD * 2);
    unsigned short* Wr    = (unsigned short*)alloc((size_t)2 * 2048 * 768 * 2);
    float*          bias2 = (float*)alloc((size_t)2 * 2048 * 4);
    unsigned short* h0buf = (unsigned short*)alloc((size_t)2 * BB * HID * 2);
    unsigned short* hsf   = (unsigned short*)alloc((size_t)TT * BB * HID * 2);
    unsigned short* hsb   = (unsigned short*)alloc((size_t)TT * BB * HID * 2);
    float*          emis  = (float*)alloc((size_t)TT * BB * KTAG * 4);
    unsigned short* fcWr  = (unsigned short*)alloc((size_t)16 * 1024 * 2);
    unsigned int*   ctrl  = (unsigned int*)alloc((size_t)32768 * 4);

    prologue<<<6144, 256, 0, stream>>>(x, emb, Wihf, Whhf, Wihb, Whhb, h0,
                                       bihf, bhhf, bihb, bhhb, fcW,
                                       xs, Wr, h0buf, bias2, fcWr, ctrl);

    hipFuncSetAttribute(reinterpret_cast<const void*>(lstm_persistent),
                        hipFuncAttributeMaxDynamicSharedMemorySize, SMEM_BYTES);
    {
        const unsigned short* p_xs = xs; const unsigned short* p_Wr = Wr;
        const float* p_bias2 = bias2; const int* p_lens = lens;
        const unsigned short* p_h0 = h0buf; const float* p_c0 = c0;
        unsigned short* p_hsf = hsf; unsigned short* p_hsb = hsb;
        unsigned int* p_ctrl = ctrl;
        void* args[9] = { &p_xs, &p_Wr, &p_bias2, &p_lens, &p_h0, &p_c0,
                          &p_hsf, &p_hsb, &p_ctrl };
        hipError_t e = hipLaunchCooperativeKernel(
            reinterpret_cast<const void*>(lstm_persistent),
            dim3(256), dim3(256), args, (unsigned)SMEM_BYTES, stream);
        if (e != hipSuccess) {
            lstm_persistent<<<256, 256, SMEM_BYTES, stream>>>(
                xs, Wr, bias2, lens, h0buf, c0, hsf, hsb, ctrl);
        }
    }

    emissions_mfma<<<512, 256, 0, stream>>>(hsf, hsb, fcWr, fcb, emis);
    crf_gold<<<BB, 128, 0, stream>>>(emis, lens, tags, trans, out);
}

// Round 11
// 2718.984 us; speedup vs baseline: 1.2673x; 1.0234x over previous
//
#include <hip/hip_runtime.h>
#include <hip/hip_bf16.h>

#define TT 256
#define BB 128
#define EMBD 256
#define HID 512
#define KTAG 12
#define START_TAG 10
#define STOP_TAG 11
#define SMEM_BYTES 148608 // 96KB W + 48KB A + 1.2KB hrep

typedef __attribute__((ext_vector_type(8))) short short8;
typedef __attribute__((ext_vector_type(4))) float f32x4;

__device__ __forceinline__ unsigned short f2bf(float f) {
    union { float f; unsigned int u; } v; v.f = f;
    unsigned int r = v.u + 0x7fffu + ((v.u >> 16) & 1u);   // RNE
    return (unsigned short)(r >> 16);
}
__device__ __forceinline__ float fsig(float x) {
    return __fdividef(1.0f, 1.0f + __expf(-x));
}
__device__ __forceinline__ float ftanh(float x) {
    return 2.0f * __fdividef(1.0f, 1.0f + __expf(-2.0f * x)) - 1.0f;
}
__device__ __forceinline__ void gll16(const void* g, void* l) {
    __builtin_amdgcn_global_load_lds((const __attribute__((address_space(1))) void*)g,
                                     (__attribute__((address_space(3))) void*)l, 16, 0, 0);
}
__device__ __forceinline__ void pack8(const float* src, unsigned short* dst) {
    float4 v0 = *(const float4*)src;
    float4 v1 = *(const float4*)(src + 4);
    unsigned short tmp[8];
    tmp[0] = f2bf(v0.x); tmp[1] = f2bf(v0.y); tmp[2] = f2bf(v0.z); tmp[3] = f2bf(v0.w);
    tmp[4] = f2bf(v1.x); tmp[5] = f2bf(v1.y); tmp[6] = f2bf(v1.z); tmp[7] = f2bf(v1.w);
    *(uint4*)dst = *(const uint4*)tmp;
}

#define SCHED_FENCE() __builtin_amdgcn_sched_barrier(0)
#define WAIT_VM4() do { asm volatile("s_waitcnt vmcnt(4)" ::: "memory"); SCHED_FENCE(); } while (0)
#define WAIT_VM0() do { asm volatile("s_waitcnt vmcnt(0)" ::: "memory"); SCHED_FENCE(); } while (0)
#define BARRIER_RAW() do { __builtin_amdgcn_s_barrier(); SCHED_FENCE(); } while (0)

// ---------------- fused prologue: xs gather | W reorder | state/bias/fcW prep ----------------
__global__ void prologue(const int* __restrict__ x, const float* __restrict__ emb,
                         const float* __restrict__ Wihf, const float* __restrict__ Whhf,
                         const float* __restrict__ Wihb, const float* __restrict__ Whhb,
                         const float* __restrict__ h0,
                         const float* __restrict__ bihf, const float* __restrict__ bhhf,
                         const float* __restrict__ bihb, const float* __restrict__ bhhb,
                         const float* __restrict__ fcW,
                         unsigned short* __restrict__ xs, unsigned short* __restrict__ Wr,
                         unsigned short* __restrict__ h0buf, float* __restrict__ bias2,
                         unsigned short* __restrict__ fcWr, unsigned int* __restrict__ ctrl)
{
    int blk = blockIdx.x;
    int tid = threadIdx.x;
    if (blk < 4096) {                       // ---- xs gather: bf16 xs[T][B][EMBD]
        int i = blk * 256 + tid;
        int chk = i & 31;
        int row = i >> 5;                   // t*BB + b
        int b = row & (BB - 1);
        int t = row >> 7;
        pack8(emb + (size_t)x[b * TT + t] * EMBD + chk * 8, xs + (size_t)row * EMBD + chk * 8);
    } else if (blk < 5632) {                // ---- W reorder -> bf16 Wr[2][2048][768]
        int i = (blk - 4096) * 256 + tid;
        int c8 = i % 96;
        int r2 = i / 96;
        int nr = r2 & 2047;
        int dir = r2 >> 11;
        int utile = nr >> 6;
        int r6 = nr & 63;
        int wm = r6 >> 4;
        int rr = r6 & 15;
        int ul = rr >> 2, g = rr & 3;
        int orow = g * HID + utile * 16 + wm * 4 + ul;
        int k0 = c8 * 8;
        const float* Wih = dir ? Wihb : Wihf;
        const float* Whh = dir ? Whhb : Whhf;
        const float* src = (k0 < EMBD) ? (Wih + (size_t)orow * EMBD + k0)
                                       : (Whh + (size_t)orow * HID + (k0 - EMBD));
        pack8(src, Wr + ((size_t)dir * 2048 + nr) * 768 + k0);
    } else {                                // ---- state / bias / fcWr / ctrl
        int i = (blk - 5632) * 256 + tid;
        if (i < 2 * BB * HID) h0buf[i] = f2bf(h0[i]);
        if (i < 2 * 2048) {
            int dir = i >> 11, j = i & 2047;
            bias2[i] = dir ? (bihb[j] + bhhb[j]) : (bihf[j] + bhhf[j]);
        }
        if (i < 16 * 1024) {
            int tag = i >> 10, k = i & 1023;
            fcWr[i] = f2bf(tag < KTAG ? fcW[tag * 1024 + k] : 0.0f);
        }
        if (i < 2048) ctrl[i] = 0u;
    }
}

// ---------------- persistent BiLSTM ----------------
// 256 blocks x 256 threads, 1 block/CU. grp = blk&7 (dir=grp>>2, btile=grp&3), utile = blk>>3.
// MFMA operand-swapped (A=W, B=[xs|h]) -> in-register pointwise (R6-verified).
// Sync: R8-proven fabric — per-WAVE flags, relaxed agent atomics, all blocks poll with
// 64 lanes via 8B loads. Publish drain overlapped with xs(t+1) staging via vmcnt(4).
// R11: group-maxlen step trim (proven R10): run TTs = max(lengths[slab]) steps.
__launch_bounds__(256, 1)
__global__ void lstm_persistent(
    const unsigned short* __restrict__ xs, const unsigned short* __restrict__ Wr,
    const float* __restrict__ bias2, const int* __restrict__ lengths,
    const unsigned short* __restrict__ h0buf, const float* __restrict__ c0,
    unsigned short* __restrict__ hsf, unsigned short* __restrict__ hsb,
    unsigned int* __restrict__ ctrl)
{
    extern __shared__ char smem[];
    unsigned short* Wlds = (unsigned short*)smem;                     // 98304 B
    unsigned short* Abuf = (unsigned short*)(smem + 98304);           // 49152 B
    unsigned short* hrep = (unsigned short*)(smem + 147456);          // [32][18] = 1152 B
    __shared__ int s_ml;

    const int blk = blockIdx.x;
    const int grp = blk & 7;
    const int dir = grp >> 2;
    const int btile = grp & 3;
    const int utile = blk >> 3;          // 0..31
    const int bg0 = btile * 32;

    const int tid = threadIdx.x;
    const int w = tid >> 6;
    const int l = tid & 63;
    const int l15 = l & 15, l16 = l >> 4;

    unsigned int* wflags = ctrl + 64 + grp * 128;      // per-wave flags [128]
    unsigned int* myflag = wflags + utile * 4 + w;

    unsigned short* hs = dir ? hsb : hsf;
    unsigned int* hs_u32 = (unsigned int*)hs;

    // ---- group maxlen: run TTs steps; skipped steps are all-masked (state carries)
    {
        int v = (tid < 32) ? lengths[bg0 + tid] : 0;
        if (tid < 64) {
            #pragma unroll
            for (int off = 32; off >= 1; off >>= 1) v = max(v, __shfl_xor(v, off, 64));
            if (tid == 0) s_ml = v;
        }
    }
    __syncthreads();
    const int TTs = s_ml;

    // ---- issue resident-W stage + xs(k=0) stage (drained by first loop-top sync)
    {
        const unsigned short* src0 =
            Wr + ((size_t)(dir * 2048 + utile * 64) + (w * 16 + l15)) * 768 + l16 * 8;
        #pragma unroll
        for (int ks = 0; ks < 24; ks++)
            gll16(src0 + ks * 32, Wlds + (w * 24 + ks) * 512);
    }
    {
        int mm = w & 1, ksb = (w >> 1) * 4;
        const int t0 = dir ? (TTs - 1) : 0;
        const unsigned short* asrc =
            xs + ((size_t)t0 * BB + (bg0 + mm * 16 + l15)) * EMBD + l16 * 8;
        #pragma unroll
        for (int q = 0; q < 4; q++)
            gll16(asrc + (ksb + q) * 32, Abuf + (mm * 24 + ksb + q) * 512);
    }

    // ---- per-thread state: (unit u, batches bA=bg0+l15 and bB=bg0+16+l15)
    const int u = utile * 16 + w * 4 + l16;
    const int bA = bg0 + l15, bB = bg0 + 16 + l15;
    const int lenA = lengths[bA], lenB = lengths[bB];
    float cA = c0[((size_t)dir * BB + bA) * HID + u];
    float cB = c0[((size_t)dir * BB + bB) * HID + u];
    float bias_r[4];
    #pragma unroll
    for (int g = 0; g < 4; g++) bias_r[g] = bias2[dir * 2048 + g * 512 + u];

    for (int k = 0; k < TTs; k++) {
        const int t = dir ? (TTs - 1 - k) : k;

        __syncthreads();                 // xs(t) staged (W too at k==0); full drain

        f32x4 aA0 = {bias_r[0], bias_r[1], bias_r[2], bias_r[3]};
        f32x4 aB0 = {bias_r[0], bias_r[1], bias_r[2], bias_r[3]};
        f32x4 aA1 = {0.f,0.f,0.f,0.f}, aB1 = {0.f,0.f,0.f,0.f};
        auto mstep = [&](int ks, f32x4& xA, f32x4& xB) {
            short8 a  = *(const short8*)(Wlds + ((w * 24 + ks) << 9) + (l << 3));
            short8 b0 = *(const short8*)(Abuf + (ks << 9) + (l << 3));
            short8 b1 = *(const short8*)(Abuf + ((24 + ks) << 9) + (l << 3));
            xA = __builtin_amdgcn_mfma_f32_16x16x32_bf16(a, b0, xA, 0, 0, 0);
            xB = __builtin_amdgcn_mfma_f32_16x16x32_bf16(a, b1, xB, 0, 0, 0);
        };
        #pragma unroll
        for (int ks = 0; ks < 8; ks += 2) { mstep(ks, aA0, aB0); mstep(ks + 1, aA1, aB1); }

        // ---- wait for group h(t_prev): 128 per-wave flags, 8B loads, pipelined poll
        if (k > 0) {
            if (tid < 64) {
                unsigned tgt = (unsigned)k;
                const unsigned long long* fp =
                    (const unsigned long long*)(wflags + 2 * (tid & 63));
                unsigned long long v0 = __hip_atomic_load(fp, __ATOMIC_RELAXED,
                                                          __HIP_MEMORY_SCOPE_AGENT);
                unsigned long long v1 = __hip_atomic_load(fp, __ATOMIC_RELAXED,
                                                          __HIP_MEMORY_SCOPE_AGENT);
                while (true) {
                    bool ok = ((unsigned)v0 >= tgt) && ((unsigned)(v0 >> 32) >= tgt);
                    if (__all(ok)) break;
                    v0 = v1;
                    v1 = __hip_atomic_load(fp, __ATOMIC_RELAXED, __HIP_MEMORY_SCOPE_AGENT);
                }
            }
            __syncthreads();
        }
        const unsigned short* hsrc = (k == 0)
            ? (h0buf + (size_t)dir * BB * HID)
            : (hs + (size_t)(dir ? (t + 1) : (t - 1)) * BB * HID);

        // ---- stage h part (ks 8..23), two-phase overlap with MFMA
        {
            int mm = w & 1, ksb = 8 + (w >> 1) * 8;
            const unsigned short* asrcH = hsrc + (size_t)(bg0 + mm * 16 + l15) * HID + l16 * 8;
            #pragma unroll
            for (int q = 0; q < 8; q++)
                gll16(asrcH + ((ksb + q) * 32 - 256), Abuf + (mm * 24 + ksb + q) * 512);
        }
        SCHED_FENCE();
        WAIT_VM4();                      // own first-4 h loads landed
        BARRIER_RAW();                   // all waves' first-4 landed: ks{8-11,16-19} ready
        #pragma unroll
        for (int q = 0; q < 4; q++) { mstep(8 + q, aA0, aB0); mstep(16 + q, aA1, aB1); }
        WAIT_VM0();                      // remaining h loads landed
        BARRIER_RAW();                   // ks{12-15,20-23} ready
        #pragma unroll
        for (int q = 0; q < 4; q++) { mstep(12 + q, aA0, aB0); mstep(20 + q, aA1, aB1); }
        f32x4 accA = aA0 + aA1;
        f32x4 accB = aB0 + aB1;

        // ---- in-register pointwise (gate order i,f,g,o = acc[0..3]; bias already in acc)
        {
            const int ksn = 8 + (u >> 5), kin = u & 31;
            const int baseA = ksn * 512 + ((kin >> 3) * 16 + l15) * 8 + (kin & 7);
            const int baseB = (24 + ksn) * 512 + ((kin >> 3) * 16 + l15) * 8 + (kin & 7);
            float cnA = fsig(accA[1]) * cA + fsig(accA[0]) * ftanh(accA[2]);
            float hnA = fsig(accA[3]) * ftanh(cnA);
            float cnB = fsig(accB[1]) * cB + fsig(accB[0]) * ftanh(accB[2]);
            float hnB = fsig(accB[3]) * ftanh(cnB);
            bool mA = t < lenA, mB = t < lenB;
            unsigned short hvA = mA ? f2bf(hnA) : Abuf[baseA];  // carried h from staged frag
            unsigned short hvB = mB ? f2bf(hnB) : Abuf[baseB];
            cA = mA ? cnA : cA;
            cB = mB ? cnB : cB;
            hrep[l15 * 18 + w * 4 + l16]        = hvA;
            hrep[(16 + l15) * 18 + w * 4 + l16] = hvB;
        }
        __syncthreads();                 // hrep visible (lgkm drain; vmcnt already 0)

        // ---- packed publish, then xs(t+1) issue, then counted drain, then per-wave flag
        {
            int bl = tid >> 3, up = tid & 7;
            unsigned v0 = hrep[bl * 18 + up * 2];
            unsigned v1 = hrep[bl * 18 + up * 2 + 1];
            unsigned pk = v0 | (v1 << 16);
            size_t widx = (((size_t)t * BB + (bg0 + bl)) * HID + utile * 16 + up * 2) >> 1;
            __hip_atomic_store(hs_u32 + widx, pk, __ATOMIC_RELAXED, __HIP_MEMORY_SCOPE_AGENT);
        }
        SCHED_FENCE();
        if (k < TTs - 1) {
            const int tn = dir ? (TTs - 2 - k) : (k + 1);
            int mm = w & 1, ksb = (w >> 1) * 4;
            const unsigned short* asrc =
                xs + ((size_t)tn * BB + (bg0 + mm * 16 + l15)) * EMBD + l16 * 8;
            #pragma unroll
            for (int q = 0; q < 4; q++)
                gll16(asrc + (ksb + q) * 32, Abuf + (mm * 24 + ksb + q) * 512);
            SCHED_FENCE();
            WAIT_VM4();                  // oldest (publish store) acked; xs still in flight
            if (l == 0)
                __hip_atomic_store(myflag, (unsigned)(k + 1), __ATOMIC_RELAXED,
                                   __HIP_MEMORY_SCOPE_AGENT);
        }
        // loop-top __syncthreads re-syncs block and drains xs loads
    }
}

// ---------------- emissions MFMA GEMM, fcWr LDS-staged, 32 rows/wave ----------------
// 256 blocks x 4 waves; block stages bf16 fcWr[16][1024] (32KB) once; wave computes 2 row-tiles.
__global__ void emissions_mfma(const unsigned short* __restrict__ hsf,
                               const unsigned short* __restrict__ hsb,
                               const unsigned short* __restrict__ fcWr,
                               const float* __restrict__ fcb, float* __restrict__ emis)
{
    __shared__ unsigned short Wl[16 * 1024];
    int tid = threadIdx.x;
    #pragma unroll
    for (int p = 0; p < 8; p++) {
        int i = (p * 256 + tid) * 8;
        *(uint4*)(Wl + i) = *(const uint4*)(fcWr + i);
    }
    __syncthreads();
    int w = tid >> 6, l = tid & 63;
    int l15 = l & 15, l16 = l >> 4;
    float bval = fcb[l15 < KTAG ? l15 : 0];
    #pragma unroll
    for (int tile = 0; tile < 2; tile++) {
        int rowbase = ((blockIdx.x * 4 + w) * 2 + tile) * 16;
        f32x4 acc0 = {0.f,0.f,0.f,0.f}, acc1 = {0.f,0.f,0.f,0.f};
        auto estep = [&](const unsigned short* hsp, int ks, f32x4& acc) {
            short8 av = *(const short8*)(hsp + (size_t)(rowbase + l15) * HID + (ks & 15) * 32 + l16 * 8);
            short8 bv = *(const short8*)(Wl + l15 * 1024 + ks * 32 + l16 * 8);
            acc = __builtin_amdgcn_mfma_f32_16x16x32_bf16(av, bv, acc, 0, 0, 0);
        };
        #pragma unroll
        for (int ks = 0; ks < 16; ks += 2) { estep(hsf, ks, acc0); estep(hsf, ks + 1, acc1); }
        #pragma unroll
        for (int ks = 16; ks < 32; ks += 2) { estep(hsb, ks, acc0); estep(hsb, ks + 1, acc1); }
        f32x4 acc = acc0 + acc1;
        if (l15 < KTAG) {
            #pragma unroll
            for (int r = 0; r < 4; r++)
                emis[(size_t)(rowbase + 4 * l16 + r) * KTAG + l15] = acc[r] + bval;
        }
    }
}

// ---------------- fused CRF partition (wave 0) + gold (wave 1) ----------------
__global__ void crf_gold(const float* __restrict__ emis, const int* __restrict__ lengths,
                         const int* __restrict__ tags, const float* __restrict__ trans,
                         float* __restrict__ out)
{
    __shared__ float s_logz, s_gold;
    int b = blockIdx.x;
    int tid = threadIdx.x;   // 128
    int len = lengths[b];
    if (tid < 64) {
        int lane = tid;
        float trow[KTAG];
        #pragma unroll
        for (int j = 0; j < KTAG; j++)
            trow[j] = (lane < KTAG) ? trans[lane * KTAG + j] : -1e30f;
        float alpha = (lane == START_TAG) ? 0.0f : -10000.0f;
        float e_cur = (lane < KTAG) ? emis[(size_t)b * KTAG + lane] : 0.0f;
        for (int t = 0; t < len; t++) {
            int tn = (t + 1 < TT) ? t + 1 : t;
            float e_next = (lane < KTAG) ? emis[(size_t)(tn * BB + b) * KTAG + lane] : 0.0f;
            float sc[KTAG];
            #pragma unroll
            for (int j = 0; j < KTAG; j++) sc[j] = __shfl(alpha, j, 64) + trow[j];
            float m = sc[0];
            #pragma unroll
            for (int j = 1; j < KTAG; j++) m = fmaxf(m, sc[j]);
            float ssum = 0.0f;
            #pragma unroll
            for (int j = 0; j < KTAG; j++) ssum += __expf(sc[j] - m);
            float anew = m + __logf(ssum) + e_cur;
            alpha = (lane < KTAG) ? anew : alpha;
            e_cur = e_next;
        }
        float v = (lane < KTAG) ? (alpha + trans[STOP_TAG * KTAG + lane]) : -1e30f;
        float m = v;
        #pragma unroll
        for (int off = 1; off < 16; off <<= 1) m = fmaxf(m, __shfl_xor(m, off, 64));
        float e = __expf(v - m);
        #pragma unroll
        for (int off = 1; off < 16; off <<= 1) e += __shfl_xor(e, off, 64);
        if (lane == 0) s_logz = m + __logf(e);
    } else {
        int l2 = tid - 64;
        float part = 0.0f;
        #pragma unroll
        for (int q = 0; q < 4; q++) {
            int t = l2 + q * 64;
            if (t < len) {
                int nxt = tags[b * TT + t];
                int prev = t ? tags[b * TT + t - 1] : START_TAG;
                part += trans[nxt * KTAG + prev] + emis[(size_t)(t * BB + b) * KTAG + nxt];
            }
        }
        #pragma unroll
        for (int off = 1; off < 64; off <<= 1) part += __shfl_xor(part, off, 64);
        if (l2 == 0) s_gold = part + trans[STOP_TAG * KTAG + tags[b * TT + len - 1]];
    }
    __syncthreads();
    if (tid == 0) out[b] = s_logz - s_gold;
}

extern "C" void kernel_launch(void* const* d_in, const int* in_sizes, int n_in,
                              void* d_out, int out_size, void* d_ws, size_t ws_size,
                              hipStream_t stream)
{
    (void)in_sizes; (void)n_in; (void)out_size; (void)ws_size;
    const int*   x     = (const int*)d_in[0];
    const int*   lens  = (const int*)d_in[1];
    const int*   tags  = (const int*)d_in[2];
    const float* emb   = (const float*)d_in[3];
    const float* Wihf  = (const float*)d_in[4];
    const float* Whhf  = (const float*)d_in[5];
    const float* bihf  = (const float*)d_in[6];
    const float* bhhf  = (const float*)d_in[7];
    const float* Wihb  = (const float*)d_in[8];
    const float* Whhb  = (const float*)d_in[9];
    const float* bihb  = (const float*)d_in[10];
    const float* bhhb  = (const float*)d_in[11];
    const float* fcW   = (const float*)d_in[12];
    const float* fcb   = (const float*)d_in[13];
    const float* trans = (const float*)d_in[14];
    const float* h0    = (const float*)d_in[15];
    const float* c0    = (const float*)d_in[16];
    float* out = (float*)d_out;

    char* ws = (char*)d_ws;
    size_t off = 0;
    auto alloc = [&](size_t bytes) {
        void* p = ws + off;
        off += (bytes + 255) & ~(size_t)255;
        return p;
    };
    unsigned short* xs    = (unsigned short*)alloc((size_t)TT * BB * EMBD * 2);
    unsigned short* Wr    = (unsigned short*)alloc((size_t)2 * 2048 * 768 * 2);
    float*          bias2 = (float*)alloc((size_t)2 * 2048 * 4);
    unsigned short* h0buf = (unsigned short*)alloc((size_t)2 * BB * HID * 2);
    unsigned short* hsf   = (unsigned short*)alloc((size_t)TT * BB * HID * 2);
    unsigned short* hsb   = (unsigned short*)alloc((size_t)TT * BB * HID * 2);
    float*          emis  = (float*)alloc((size_t)TT * BB * KTAG * 4);
    unsigned short* fcWr  = (unsigned short*)alloc((size_t)16 * 1024 * 2);
    unsigned int*   ctrl  = (unsigned int*)alloc((size_t)2048 * 4);

    prologue<<<6144, 256, 0, stream>>>(x, emb, Wihf, Whhf, Wihb, Whhb, h0,
                                       bihf, bhhf, bihb, bhhb, fcW,
                                       xs, Wr, h0buf, bias2, fcWr, ctrl);

    hipFuncSetAttribute(reinterpret_cast<const void*>(lstm_persistent),
                        hipFuncAttributeMaxDynamicSharedMemorySize, SMEM_BYTES);
    {
        const unsigned short* p_xs = xs; const unsigned short* p_Wr = Wr;
        const float* p_bias2 = bias2; const int* p_lens = lens;
        const unsigned short* p_h0 = h0buf; const float* p_c0 = c0;
        unsigned short* p_hsf = hsf; unsigned short* p_hsb = hsb;
        unsigned int* p_ctrl = ctrl;
        void* args[9] = { &p_xs, &p_Wr, &p_bias2, &p_lens, &p_h0, &p_c0,
                          &p_hsf, &p_hsb, &p_ctrl };
        hipError_t e = hipLaunchCooperativeKernel(
            reinterpret_cast<const void*>(lstm_persistent),
            dim3(256), dim3(256), args, (unsigned)SMEM_BYTES, stream);
        if (e != hipSuccess) {
            lstm_persistent<<<256, 256, SMEM_BYTES, stream>>>(
                xs, Wr, bias2, lens, h0buf, c0, hsf, hsb, ctrl);
        }
    }

    emissions_mfma<<<256, 256, 0, stream>>>(hsf, hsb, fcWr, fcb, emis);
    crf_gold<<<BB, 128, 0, stream>>>(emis, lens, tags, trans, out);
}

// Round 12
// 1065.028 us; speedup vs baseline: 3.2353x; 2.5530x over previous
//
#include <hip/hip_runtime.h>
#include <hip/hip_bf16.h>

#define TT 256
#define BB 128
#define EMBD 256
#define HID 512
#define KTAG 12
#define START_TAG 10
#define STOP_TAG 11
#define SMEM_BYTES 148608 // 96KB W + 48KB A + 1.2KB hrep

typedef __attribute__((ext_vector_type(8))) short short8;
typedef __attribute__((ext_vector_type(4))) float f32x4;

__device__ __forceinline__ unsigned short f2bf(float f) {
    union { float f; unsigned int u; } v; v.f = f;
    unsigned int r = v.u + 0x7fffu + ((v.u >> 16) & 1u);   // RNE
    return (unsigned short)(r >> 16);
}
__device__ __forceinline__ float fsig(float x) {
    return __fdividef(1.0f, 1.0f + __expf(-x));
}
__device__ __forceinline__ float ftanh(float x) {
    return 2.0f * __fdividef(1.0f, 1.0f + __expf(-2.0f * x)) - 1.0f;
}
__device__ __forceinline__ void gll16(const void* g, void* l) {
    __builtin_amdgcn_global_load_lds((const __attribute__((address_space(1))) void*)g,
                                     (__attribute__((address_space(3))) void*)l, 16, 0, 0);
}
__device__ __forceinline__ void pack8(const float* src, unsigned short* dst) {
    float4 v0 = *(const float4*)src;
    float4 v1 = *(const float4*)(src + 4);
    unsigned short tmp[8];
    tmp[0] = f2bf(v0.x); tmp[1] = f2bf(v0.y); tmp[2] = f2bf(v0.z); tmp[3] = f2bf(v0.w);
    tmp[4] = f2bf(v1.x); tmp[5] = f2bf(v1.y); tmp[6] = f2bf(v1.z); tmp[7] = f2bf(v1.w);
    *(uint4*)dst = *(const uint4*)tmp;
}

#define SCHED_FENCE() __builtin_amdgcn_sched_barrier(0)
#define WAIT_VM4() do { asm volatile("s_waitcnt vmcnt(4)" ::: "memory"); SCHED_FENCE(); } while (0)
#define WAIT_VM0() do { asm volatile("s_waitcnt vmcnt(0)" ::: "memory"); SCHED_FENCE(); } while (0)
#define BARRIER_RAW() do { __builtin_amdgcn_s_barrier(); SCHED_FENCE(); } while (0)

// ---------------- fused prologue: xs gather | W reorder | state/bias/fcW prep ----------------
__global__ void prologue(const int* __restrict__ x, const float* __restrict__ emb,
                         const float* __restrict__ Wihf, const float* __restrict__ Whhf,
                         const float* __restrict__ Wihb, const float* __restrict__ Whhb,
                         const float* __restrict__ h0,
                         const float* __restrict__ bihf, const float* __restrict__ bhhf,
                         const float* __restrict__ bihb, const float* __restrict__ bhhb,
                         const float* __restrict__ fcW,
                         unsigned short* __restrict__ xs, unsigned short* __restrict__ Wr,
                         unsigned short* __restrict__ h0buf, float* __restrict__ bias2,
                         unsigned short* __restrict__ fcWr, unsigned int* __restrict__ ctrl)
{
    int blk = blockIdx.x;
    int tid = threadIdx.x;
    if (blk < 4096) {                       // ---- xs gather: bf16 xs[T][B][EMBD]
        int i = blk * 256 + tid;
        int chk = i & 31;
        int row = i >> 5;                   // t*BB + b
        int b = row & (BB - 1);
        int t = row >> 7;
        pack8(emb + (size_t)x[b * TT + t] * EMBD + chk * 8, xs + (size_t)row * EMBD + chk * 8);
    } else if (blk < 5632) {                // ---- W reorder -> bf16 Wr[2][2048][768]
        int i = (blk - 4096) * 256 + tid;
        int c8 = i % 96;
        int r2 = i / 96;
        int nr = r2 & 2047;
        int dir = r2 >> 11;
        int utile = nr >> 6;
        int r6 = nr & 63;
        int wm = r6 >> 4;
        int rr = r6 & 15;
        int ul = rr >> 2, g = rr & 3;
        int orow = g * HID + utile * 16 + wm * 4 + ul;
        int k0 = c8 * 8;
        const float* Wih = dir ? Wihb : Wihf;
        const float* Whh = dir ? Whhb : Whhf;
        const float* src = (k0 < EMBD) ? (Wih + (size_t)orow * EMBD + k0)
                                       : (Whh + (size_t)orow * HID + (k0 - EMBD));
        pack8(src, Wr + ((size_t)dir * 2048 + nr) * 768 + k0);
    } else {                                // ---- state / bias / fcWr / ctrl
        int i = (blk - 5632) * 256 + tid;
        if (i < 2 * BB * HID) h0buf[i] = f2bf(h0[i]);
        if (i < 2 * 2048) {
            int dir = i >> 11, j = i & 2047;
            bias2[i] = dir ? (bihb[j] + bhhb[j]) : (bihf[j] + bhhf[j]);
        }
        if (i < 16 * 1024) {
            int tag = i >> 10, k = i & 1023;
            fcWr[i] = f2bf(tag < KTAG ? fcW[tag * 1024 + k] : 0.0f);
        }
        if (i < 2048) ctrl[i] = 0u;
    }
}

// ---------------- persistent BiLSTM (exact R8 body — proven 940 us) ----------------
// 256 blocks x 256 threads, 1 block/CU. grp = blk&7 (dir=grp>>2, btile=grp&3), utile = blk>>3.
// MFMA operand-swapped (A=W, B=[xs|h]) -> in-register pointwise.
// Sync: per-WAVE flags, relaxed agent atomics, all blocks poll with 64 lanes via 8B loads.
// Publish drain overlapped with xs(t+1) staging via counted vmcnt(4) (in-order acks).
// NOTE (R11 post-mortem): adding a static __shared__ + runtime loop bound (group-maxlen)
// regressed this kernel 2.7x with identical work counters — feature reverted, cause unresolved.
__launch_bounds__(256, 1)
__global__ void lstm_persistent(
    const unsigned short* __restrict__ xs, const unsigned short* __restrict__ Wr,
    const float* __restrict__ bias2, const int* __restrict__ lengths,
    const unsigned short* __restrict__ h0buf, const float* __restrict__ c0,
    unsigned short* __restrict__ hsf, unsigned short* __restrict__ hsb,
    unsigned int* __restrict__ ctrl)
{
    extern __shared__ char smem[];
    unsigned short* Wlds = (unsigned short*)smem;                     // 98304 B
    unsigned short* Abuf = (unsigned short*)(smem + 98304);           // 49152 B
    unsigned short* hrep = (unsigned short*)(smem + 147456);          // [32][18] = 1152 B

    const int blk = blockIdx.x;
    const int grp = blk & 7;
    const int dir = grp >> 2;
    const int btile = grp & 3;
    const int utile = blk >> 3;          // 0..31
    const int bg0 = btile * 32;

    const int tid = threadIdx.x;
    const int w = tid >> 6;
    const int l = tid & 63;
    const int l15 = l & 15, l16 = l >> 4;

    unsigned int* wflags = ctrl + 64 + grp * 128;      // per-wave flags [128]
    unsigned int* myflag = wflags + utile * 4 + w;

    unsigned short* hs = dir ? hsb : hsf;
    unsigned int* hs_u32 = (unsigned int*)hs;

    // ---- issue resident-W stage + xs(0) stage (drained by first loop-top sync)
    {
        const unsigned short* src0 =
            Wr + ((size_t)(dir * 2048 + utile * 64) + (w * 16 + l15)) * 768 + l16 * 8;
        #pragma unroll
        for (int ks = 0; ks < 24; ks++)
            gll16(src0 + ks * 32, Wlds + (w * 24 + ks) * 512);
    }
    {
        int mm = w & 1, ksb = (w >> 1) * 4;
        const int t0 = dir ? (TT - 1) : 0;
        const unsigned short* asrc =
            xs + ((size_t)t0 * BB + (bg0 + mm * 16 + l15)) * EMBD + l16 * 8;
        #pragma unroll
        for (int q = 0; q < 4; q++)
            gll16(asrc + (ksb + q) * 32, Abuf + (mm * 24 + ksb + q) * 512);
    }

    // ---- per-thread state: (unit u, batches bA=bg0+l15 and bB=bg0+16+l15)
    const int u = utile * 16 + w * 4 + l16;
    const int bA = bg0 + l15, bB = bg0 + 16 + l15;
    const int lenA = lengths[bA], lenB = lengths[bB];
    float cA = c0[((size_t)dir * BB + bA) * HID + u];
    float cB = c0[((size_t)dir * BB + bB) * HID + u];
    float bias_r[4];
    #pragma unroll
    for (int g = 0; g < 4; g++) bias_r[g] = bias2[dir * 2048 + g * 512 + u];

    for (int s = 0; s < TT; s++) {
        const int t = dir ? (TT - 1 - s) : s;

        __syncthreads();                 // xs(t) staged (W too at s==0); full drain

        f32x4 aA0 = {bias_r[0], bias_r[1], bias_r[2], bias_r[3]};
        f32x4 aB0 = {bias_r[0], bias_r[1], bias_r[2], bias_r[3]};
        f32x4 aA1 = {0.f,0.f,0.f,0.f}, aB1 = {0.f,0.f,0.f,0.f};
        auto mstep = [&](int ks, f32x4& xA, f32x4& xB) {
            short8 a  = *(const short8*)(Wlds + ((w * 24 + ks) << 9) + (l << 3));
            short8 b0 = *(const short8*)(Abuf + (ks << 9) + (l << 3));
            short8 b1 = *(const short8*)(Abuf + ((24 + ks) << 9) + (l << 3));
            xA = __builtin_amdgcn_mfma_f32_16x16x32_bf16(a, b0, xA, 0, 0, 0);
            xB = __builtin_amdgcn_mfma_f32_16x16x32_bf16(a, b1, xB, 0, 0, 0);
        };
        #pragma unroll
        for (int ks = 0; ks < 8; ks += 2) { mstep(ks, aA0, aB0); mstep(ks + 1, aA1, aB1); }

        // ---- wait for group h(t_prev): 128 per-wave flags, 8B loads, pipelined poll
        if (s > 0) {
            if (tid < 64) {
                unsigned tgt = (unsigned)s;
                const unsigned long long* fp =
                    (const unsigned long long*)(wflags + 2 * (tid & 63));
                unsigned long long v0 = __hip_atomic_load(fp, __ATOMIC_RELAXED,
                                                          __HIP_MEMORY_SCOPE_AGENT);
                unsigned long long v1 = __hip_atomic_load(fp, __ATOMIC_RELAXED,
                                                          __HIP_MEMORY_SCOPE_AGENT);
                while (true) {
                    bool ok = ((unsigned)v0 >= tgt) && ((unsigned)(v0 >> 32) >= tgt);
                    if (__all(ok)) break;
                    v0 = v1;
                    v1 = __hip_atomic_load(fp, __ATOMIC_RELAXED, __HIP_MEMORY_SCOPE_AGENT);
                }
            }
            __syncthreads();
        }
        const unsigned short* hsrc = (s == 0)
            ? (h0buf + (size_t)dir * BB * HID)
            : (hs + (size_t)(dir ? (t + 1) : (t - 1)) * BB * HID);

        // ---- stage h part (ks 8..23), two-phase overlap with MFMA
        {
            int mm = w & 1, ksb = 8 + (w >> 1) * 8;
            const unsigned short* asrcH = hsrc + (size_t)(bg0 + mm * 16 + l15) * HID + l16 * 8;
            #pragma unroll
            for (int q = 0; q < 8; q++)
                gll16(asrcH + ((ksb + q) * 32 - 256), Abuf + (mm * 24 + ksb + q) * 512);
        }
        SCHED_FENCE();
        WAIT_VM4();                      // own first-4 h loads landed
        BARRIER_RAW();                   // all waves' first-4 landed: ks{8-11,16-19} ready
        #pragma unroll
        for (int q = 0; q < 4; q++) { mstep(8 + q, aA0, aB0); mstep(16 + q, aA1, aB1); }
        WAIT_VM0();                      // remaining h loads landed
        BARRIER_RAW();                   // ks{12-15,20-23} ready
        #pragma unroll
        for (int q = 0; q < 4; q++) { mstep(12 + q, aA0, aB0); mstep(20 + q, aA1, aB1); }
        f32x4 accA = aA0 + aA1;
        f32x4 accB = aB0 + aB1;

        // ---- in-register pointwise (gate order i,f,g,o = acc[0..3]; bias already in acc)
        {
            const int ksn = 8 + (u >> 5), kin = u & 31;
            const int baseA = ksn * 512 + ((kin >> 3) * 16 + l15) * 8 + (kin & 7);
            const int baseB = (24 + ksn) * 512 + ((kin >> 3) * 16 + l15) * 8 + (kin & 7);
            float cnA = fsig(accA[1]) * cA + fsig(accA[0]) * ftanh(accA[2]);
            float hnA = fsig(accA[3]) * ftanh(cnA);
            float cnB = fsig(accB[1]) * cB + fsig(accB[0]) * ftanh(accB[2]);
            float hnB = fsig(accB[3]) * ftanh(cnB);
            bool mA = t < lenA, mB = t < lenB;
            unsigned short hvA = mA ? f2bf(hnA) : Abuf[baseA];  // carried h from staged frag
            unsigned short hvB = mB ? f2bf(hnB) : Abuf[baseB];
            cA = mA ? cnA : cA;
            cB = mB ? cnB : cB;
            hrep[l15 * 18 + w * 4 + l16]        = hvA;
            hrep[(16 + l15) * 18 + w * 4 + l16] = hvB;
        }
        __syncthreads();                 // hrep visible (lgkm drain; vmcnt already 0)

        // ---- packed publish, then xs(t+1) issue, then counted drain, then per-wave flag
        {
            int bl = tid >> 3, up = tid & 7;
            unsigned v0 = hrep[bl * 18 + up * 2];
            unsigned v1 = hrep[bl * 18 + up * 2 + 1];
            unsigned pk = v0 | (v1 << 16);
            size_t widx = (((size_t)t * BB + (bg0 + bl)) * HID + utile * 16 + up * 2) >> 1;
            __hip_atomic_store(hs_u32 + widx, pk, __ATOMIC_RELAXED, __HIP_MEMORY_SCOPE_AGENT);
        }
        SCHED_FENCE();
        if (s < TT - 1) {
            const int tn = dir ? (TT - 2 - s) : (s + 1);
            int mm = w & 1, ksb = (w >> 1) * 4;
            const unsigned short* asrc =
                xs + ((size_t)tn * BB + (bg0 + mm * 16 + l15)) * EMBD + l16 * 8;
            #pragma unroll
            for (int q = 0; q < 4; q++)
                gll16(asrc + (ksb + q) * 32, Abuf + (mm * 24 + ksb + q) * 512);
            SCHED_FENCE();
            WAIT_VM4();                  // oldest (publish store) acked; xs still in flight
            if (l == 0)
                __hip_atomic_store(myflag, (unsigned)(s + 1), __ATOMIC_RELAXED,
                                   __HIP_MEMORY_SCOPE_AGENT);
        }
        // loop-top __syncthreads re-syncs block and drains xs loads
    }
}

// ---------------- emissions MFMA GEMM, fcWr LDS-staged, 32 rows/wave ----------------
// 256 blocks x 4 waves; block stages bf16 fcWr[16][1024] (32KB) once; wave computes 2 row-tiles.
__global__ void emissions_mfma(const unsigned short* __restrict__ hsf,
                               const unsigned short* __restrict__ hsb,
                               const unsigned short* __restrict__ fcWr,
                               const float* __restrict__ fcb, float* __restrict__ emis)
{
    __shared__ unsigned short Wl[16 * 1024];
    int tid = threadIdx.x;
    #pragma unroll
    for (int p = 0; p < 8; p++) {
        int i = (p * 256 + tid) * 8;
        *(uint4*)(Wl + i) = *(const uint4*)(fcWr + i);
    }
    __syncthreads();
    int w = tid >> 6, l = tid & 63;
    int l15 = l & 15, l16 = l >> 4;
    float bval = fcb[l15 < KTAG ? l15 : 0];
    #pragma unroll
    for (int tile = 0; tile < 2; tile++) {
        int rowbase = ((blockIdx.x * 4 + w) * 2 + tile) * 16;
        f32x4 acc0 = {0.f,0.f,0.f,0.f}, acc1 = {0.f,0.f,0.f,0.f};
        auto estep = [&](const unsigned short* hsp, int ks, f32x4& acc) {
            short8 av = *(const short8*)(hsp + (size_t)(rowbase + l15) * HID + (ks & 15) * 32 + l16 * 8);
            short8 bv = *(const short8*)(Wl + l15 * 1024 + ks * 32 + l16 * 8);
            acc = __builtin_amdgcn_mfma_f32_16x16x32_bf16(av, bv, acc, 0, 0, 0);
        };
        #pragma unroll
        for (int ks = 0; ks < 16; ks += 2) { estep(hsf, ks, acc0); estep(hsf, ks + 1, acc1); }
        #pragma unroll
        for (int ks = 16; ks < 32; ks += 2) { estep(hsb, ks, acc0); estep(hsb, ks + 1, acc1); }
        f32x4 acc = acc0 + acc1;
        if (l15 < KTAG) {
            #pragma unroll
            for (int r = 0; r < 4; r++)
                emis[(size_t)(rowbase + 4 * l16 + r) * KTAG + l15] = acc[r] + bval;
        }
    }
}

// ---------------- fused CRF partition (wave 0) + gold (wave 1) ----------------
__global__ void crf_gold(const float* __restrict__ emis, const int* __restrict__ lengths,
                         const int* __restrict__ tags, const float* __restrict__ trans,
                         float* __restrict__ out)
{
    __shared__ float s_logz, s_gold;
    int b = blockIdx.x;
    int tid = threadIdx.x;   // 128
    int len = lengths[b];
    if (tid < 64) {
        int lane = tid;
        float trow[KTAG];
        #pragma unroll
        for (int j = 0; j < KTAG; j++)
            trow[j] = (lane < KTAG) ? trans[lane * KTAG + j] : -1e30f;
        float alpha = (lane == START_TAG) ? 0.0f : -10000.0f;
        float e_cur = (lane < KTAG) ? emis[(size_t)b * KTAG + lane] : 0.0f;
        for (int t = 0; t < len; t++) {
            int tn = (t + 1 < TT) ? t + 1 : t;
            float e_next = (lane < KTAG) ? emis[(size_t)(tn * BB + b) * KTAG + lane] : 0.0f;
            float sc[KTAG];
            #pragma unroll
            for (int j = 0; j < KTAG; j++) sc[j] = __shfl(alpha, j, 64) + trow[j];
            float m = sc[0];
            #pragma unroll
            for (int j = 1; j < KTAG; j++) m = fmaxf(m, sc[j]);
            float ssum = 0.0f;
            #pragma unroll
            for (int j = 0; j < KTAG; j++) ssum += __expf(sc[j] - m);
            float anew = m + __logf(ssum) + e_cur;
            alpha = (lane < KTAG) ? anew : alpha;
            e_cur = e_next;
        }
        float v = (lane < KTAG) ? (alpha + trans[STOP_TAG * KTAG + lane]) : -1e30f;
        float m = v;
        #pragma unroll
        for (int off = 1; off < 16; off <<= 1) m = fmaxf(m, __shfl_xor(m, off, 64));
        float e = __expf(v - m);
        #pragma unroll
        for (int off = 1; off < 16; off <<= 1) e += __shfl_xor(e, off, 64);
        if (lane == 0) s_logz = m + __logf(e);
    } else {
        int l2 = tid - 64;
        float part = 0.0f;
        #pragma unroll
        for (int q = 0; q < 4; q++) {
            int t = l2 + q * 64;
            if (t < len) {
                int nxt = tags[b * TT + t];
                int prev = t ? tags[b * TT + t - 1] : START_TAG;
                part += trans[nxt * KTAG + prev] + emis[(size_t)(t * BB + b) * KTAG + nxt];
            }
        }
        #pragma unroll
        for (int off = 1; off < 64; off <<= 1) part += __shfl_xor(part, off, 64);
        if (l2 == 0) s_gold = part + trans[STOP_TAG * KTAG + tags[b * TT + len - 1]];
    }
    __syncthreads();
    if (tid == 0) out[b] = s_logz - s_gold;
}

extern "C" void kernel_launch(void* const* d_in, const int* in_sizes, int n_in,
                              void* d_out, int out_size, void* d_ws, size_t ws_size,
                              hipStream_t stream)
{
    (void)in_sizes; (void)n_in; (void)out_size; (void)ws_size;
    const int*   x     = (const int*)d_in[0];
    const int*   lens  = (const int*)d_in[1];
    const int*   tags  = (const int*)d_in[2];
    const float* emb   = (const float*)d_in[3];
    const float* Wihf  = (const float*)d_in[4];
    const float* Whhf  = (const float*)d_in[5];
    const float* bihf  = (const float*)d_in[6];
    const float* bhhf  = (const float*)d_in[7];
    const float* Wihb  = (const float*)d_in[8];
    const float* Whhb  = (const float*)d_in[9];
    const float* bihb  = (const float*)d_in[10];
    const float* bhhb  = (const float*)d_in[11];
    const float* fcW   = (const float*)d_in[12];
    const float* fcb   = (const float*)d_in[13];
    const float* trans = (const float*)d_in[14];
    const float* h0    = (const float*)d_in[15];
    const float* c0    = (const float*)d_in[16];
    float* out = (float*)d_out;

    char* ws = (char*)d_ws;
    size_t off = 0;
    auto alloc = [&](size_t bytes) {
        void* p = ws + off;
        off += (bytes + 255) & ~(size_t)255;
        return p;
    };
    unsigned short* xs    = (unsigned short*)alloc((size_t)TT * BB * EMBD * 2);
    unsigned short* Wr    = (unsigned short*)alloc((size_t)2 * 2048 * 768 * 2);
    float*          bias2 = (float*)alloc((size_t)2 * 2048 * 4);
    unsigned short* h0buf = (unsigned short*)alloc((size_t)2 * BB * HID * 2);
    unsigned short* hsf   = (unsigned short*)alloc((size_t)TT * BB * HID * 2);
    unsigned short* hsb   = (unsigned short*)alloc((size_t)TT * BB * HID * 2);
    float*          emis  = (float*)alloc((size_t)TT * BB * KTAG * 4);
    unsigned short* fcWr  = (unsigned short*)alloc((size_t)16 * 1024 * 2);
    unsigned int*   ctrl  = (unsigned int*)alloc((size_t)2048 * 4);

    prologue<<<6144, 256, 0, stream>>>(x, emb, Wihf, Whhf, Wihb, Whhb, h0,
                                       bihf, bhhf, bihb, bhhb, fcW,
                                       xs, Wr, h0buf, bias2, fcWr, ctrl);

    hipFuncSetAttribute(reinterpret_cast<const void*>(lstm_persistent),
                        hipFuncAttributeMaxDynamicSharedMemorySize, SMEM_BYTES);
    {
        const unsigned short* p_xs = xs; const unsigned short* p_Wr = Wr;
        const float* p_bias2 = bias2; const int* p_lens = lens;
        const unsigned short* p_h0 = h0buf; const float* p_c0 = c0;
        unsigned short* p_hsf = hsf; unsigned short* p_hsb = hsb;
        unsigned int* p_ctrl = ctrl;
        void* args[9] = { &p_xs, &p_Wr, &p_bias2, &p_lens, &p_h0, &p_c0,
                          &p_hsf, &p_hsb, &p_ctrl };
        hipError_t e = hipLaunchCooperativeKernel(
            reinterpret_cast<const void*>(lstm_persistent),
            dim3(256), dim3(256), args, (unsigned)SMEM_BYTES, stream);
        if (e != hipSuccess) {
            lstm_persistent<<<256, 256, SMEM_BYTES, stream>>>(
                xs, Wr, bias2, lens, h0buf, c0, hsf, hsb, ctrl);
        }
    }

    emissions_mfma<<<256, 256, 0, stream>>>(hsf, hsb, fcWr, fcb, emis);
    crf_gold<<<BB, 128, 0, stream>>>(emis, lens, tags, trans, out);
}